// Round 3
// baseline (5104.438 us; speedup 1.0000x reference)
//
#include <hip/hip_runtime.h>
#include <cstdint>
#include <cstddef>

#define BB 512
#define TT 1024
#define FF 128
#define HH 128
#define AA 16

// ---------------- Phase 1: cur1[b][t][h] = x[b,t,:] . W1[h,:] + b1[h] ----------------
// Thread per (b,t). x row in VGPRs (per-lane addresses -> full MLP);
// W1 rows are wave-uniform -> scalar loads. 4-strand order preserved bitwise.
__global__ __launch_bounds__(256, 2) void gemm_cur1(
    const float* __restrict__ X,    // (B,T,F)
    const float* __restrict__ W1,   // (H,F)
    const float* __restrict__ b1,   // (H)
    float* __restrict__ cur1,       // (B,Tc,H)
    int t0, int Tc)
{
    const int tid = threadIdx.x;
    const int b = blockIdx.y;
    const int t = blockIdx.x * 256 + tid;   // t within chunk

    const float* xr = X + ((size_t)b * TT + t0 + t) * FF;
    float4 xq[32];
    #pragma unroll
    for (int q = 0; q < 32; ++q) {
        float4 v = ((const float4*)xr)[q];
        asm volatile("" : "+v"(v.x), "+v"(v.y), "+v"(v.z), "+v"(v.w));
        xq[q] = v;
    }

    float* cr = cur1 + ((size_t)b * Tc + t) * HH;

    #pragma unroll 1
    for (int h = 0; h < HH; h += 4) {
        float o[4];
        #pragma unroll
        for (int hh = 0; hh < 4; ++hh) {
            const float4* w4 = (const float4*)(W1 + (size_t)(h + hh) * FF);
            float s0 = 0.f, s1 = 0.f, s2 = 0.f, s3 = 0.f;
            #pragma unroll
            for (int q = 0; q < 32; ++q) {
                float4 w = w4[q];
                s0 = fmaf(xq[q].x, w.x, s0);
                s1 = fmaf(xq[q].y, w.y, s1);
                s2 = fmaf(xq[q].z, w.z, s2);
                s3 = fmaf(xq[q].w, w.w, s3);
            }
            o[hh] = ((s0 + s1) + (s2 + s3)) + b1[h + hh];
        }
        float4 st; st.x = o[0]; st.y = o[1]; st.z = o[2]; st.w = o[3];
        ((float4*)cr)[h >> 2] = st;
    }
}

// ---------------- Phase 2: scan. 2 waves per batch (one per j-half). ----------------
// Each wave REPLICATES LIF1 for all 128 h (elementwise, cheap) so spk1 masks
// come from two local __ballot()s: zero LDS, zero barriers. Each lane holds
// one W2 row (128 VGPRs, fits arch budget -> no spill). spk2 half-masks go
// to global; `out` is computed by a separate parallel kernel.
__global__ __launch_bounds__(64, 1) void scan_lif(
    const float* __restrict__ cur1,    // (B,Tc,H)
    const float* __restrict__ mem_in,  // (B,2,H)
    float* __restrict__ mem_out,
    const float* __restrict__ beta1,
    const float* __restrict__ W2,      // (H,H)
    const float* __restrict__ b2,
    const float* __restrict__ beta2,
    unsigned long long* __restrict__ maskbuf,  // (B,Tc,2)
    int Tc)
{
    const int lane = threadIdx.x;
    const int b = blockIdx.x >> 1;
    const int half = blockIdx.x & 1;
    const int j = half * 64 + lane;

    // W2 row j pinned in VGPRs (128 regs).
    float w2r[128];
    {
        const float4* wp = (const float4*)(W2 + (size_t)j * HH);
        #pragma unroll
        for (int q = 0; q < 32; ++q) {
            float4 v = wp[q];
            asm volatile("" : "+v"(v.x), "+v"(v.y), "+v"(v.z), "+v"(v.w));
            w2r[4*q+0] = v.x; w2r[4*q+1] = v.y; w2r[4*q+2] = v.z; w2r[4*q+3] = v.w;
        }
    }

    float mem10 = mem_in[b * 256 + lane];
    float mem11 = mem_in[b * 256 + 64 + lane];
    float mem2  = mem_in[b * 256 + 128 + j];
    const float bt10 = fminf(fmaxf(beta1[lane], 0.f), 1.f);
    const float bt11 = fminf(fmaxf(beta1[lane + 64], 0.f), 1.f);
    const float bt2  = fminf(fmaxf(beta2[j], 0.f), 1.f);
    const float b2j  = b2[j];

    const float* cb = cur1 + (size_t)b * Tc * HH;
    unsigned long long* mb = maskbuf + (size_t)b * Tc * 2 + half;

    // 4-deep prefetch pipeline for cur1 (HBM latency ~900 cyc > step ~300 cyc).
    float p0[4], p1[4];
    #pragma unroll
    for (int i = 0; i < 4; ++i) {
        int tt = (i < Tc) ? i : (Tc - 1);
        p0[i] = cb[(size_t)tt * HH + lane];
        p1[i] = cb[(size_t)tt * HH + 64 + lane];
    }

    #pragma unroll 1
    for (int t = 0; t < Tc; t += 4) {
        #pragma unroll
        for (int u = 0; u < 4; ++u) {
            const float c10 = p0[u], c11 = p1[u];
            // refill slot (consumed 4 steps later)
            int tn = t + u + 4; if (tn >= Tc) tn = Tc - 1;
            p0[u] = cb[(size_t)tn * HH + lane];
            p1[u] = cb[(size_t)tn * HH + 64 + lane];

            // ---- LIF1, replicated for both halves ----
            const float r10 = (mem10 > 1.0f) ? 1.0f : 0.0f;
            mem10 = bt10 * mem10 + c10 - r10;
            const int sp10 = (mem10 - 1.0f) > 0.0f;
            const float r11 = (mem11 > 1.0f) ? 1.0f : 0.0f;
            mem11 = bt11 * mem11 + c11 - r11;
            const int sp11 = (mem11 - 1.0f) > 0.0f;

            const unsigned long long mlo = __ballot(sp10);  // bits = h 0..63
            const unsigned long long mhi = __ballot(sp11);  // bits = h 64..127
            const unsigned mA = (unsigned)mlo, mB = (unsigned)(mlo >> 32);
            const unsigned mC = (unsigned)mhi, mD = (unsigned)(mhi >> 32);

            // ---- cur2[j]: strand order identical to rounds 1-2 ----
            float c2a = b2j, c2b = 0.f;
            #pragma unroll
            for (int h = 0; h < 32; ++h)
                c2a = fmaf(((mA >> h) & 1u) ? 1.0f : 0.0f, w2r[h], c2a);
            #pragma unroll
            for (int h = 0; h < 32; ++h)
                c2b = fmaf(((mB >> h) & 1u) ? 1.0f : 0.0f, w2r[32 + h], c2b);
            #pragma unroll
            for (int h = 0; h < 32; ++h)
                c2a = fmaf(((mC >> h) & 1u) ? 1.0f : 0.0f, w2r[64 + h], c2a);
            #pragma unroll
            for (int h = 0; h < 32; ++h)
                c2b = fmaf(((mD >> h) & 1u) ? 1.0f : 0.0f, w2r[96 + h], c2b);
            const float cur2 = c2a + c2b;

            // ---- LIF2 (own half only) ----
            const float r2 = (mem2 > 1.0f) ? 1.0f : 0.0f;
            mem2 = bt2 * mem2 + cur2 - r2;
            const int sp2 = (mem2 - 1.0f) > 0.0f;
            const unsigned long long m2 = __ballot(sp2);   // bits = j half*64 + lane

            if (lane == 0) mb[(size_t)(t + u) * 2] = m2;   // fire-and-forget
        }
    }

    if (half == 0) {
        mem_out[b * 256 + lane] = mem10;
        mem_out[b * 256 + 64 + lane] = mem11;
    }
    mem_out[b * 256 + 128 + j] = mem2;
}

// ---------------- Phase 3: out[b,t,a] = b3[a] + sum_j spk2[j] * W3[a,j] ----------------
// Thread per (b,t,a). Reproduces round-2's bitwise order:
// p_g = (pa_g + pb_g), o = b3a + ((p0+p1)+(p2+p3)).
__global__ __launch_bounds__(256, 2) void out_k(
    const unsigned long long* __restrict__ maskbuf,  // (B,Tc,2)
    const float* __restrict__ W3,   // (A,H)
    const float* __restrict__ b3,   // (A)
    float* __restrict__ out,        // (B,T,A)
    int t0, int Tc)
{
    __shared__ float W3T[HH * AA];  // [j][a]
    const int tid = threadIdx.x;
    const int b = blockIdx.y;
    const int tl = blockIdx.x * 16 + (tid >> 4);
    const int a = tid & 15;

    for (int i = tid; i < HH * AA; i += 256) {
        int aa = i >> 7, j = i & 127;
        W3T[j * AA + aa] = W3[i];
    }
    __syncthreads();

    const unsigned long long mlo = maskbuf[((size_t)b * Tc + tl) * 2 + 0];
    const unsigned long long mhi = maskbuf[((size_t)b * Tc + tl) * 2 + 1];
    const unsigned w0 = (unsigned)mlo, w1 = (unsigned)(mlo >> 32);
    const unsigned w2 = (unsigned)mhi, w3 = (unsigned)(mhi >> 32);
    const unsigned wg[4] = {w0, w1, w2, w3};

    float pg[4];
    #pragma unroll
    for (int g = 0; g < 4; ++g) {
        float pa = 0.f, pb = 0.f;
        #pragma unroll
        for (int k = 0; k < 16; ++k) {
            pa = fmaf((float)((wg[g] >> k) & 1u),        W3T[(g * 32 + k) * AA + a], pa);
            pb = fmaf((float)((wg[g] >> (k + 16)) & 1u), W3T[(g * 32 + 16 + k) * AA + a], pb);
        }
        pg[g] = pa + pb;
    }
    out[((size_t)b * TT + t0 + tl) * AA + a] = b3[a] + ((pg[0] + pg[1]) + (pg[2] + pg[3]));
}

extern "C" void kernel_launch(void* const* d_in, const int* in_sizes, int n_in,
                              void* d_out, int out_size, void* d_ws, size_t ws_size,
                              hipStream_t stream) {
    const float* X     = (const float*)d_in[0];
    const float* hid   = (const float*)d_in[1];
    const float* W1    = (const float*)d_in[2];
    const float* b1    = (const float*)d_in[3];
    const float* beta1 = (const float*)d_in[4];
    const float* W2    = (const float*)d_in[5];
    const float* b2    = (const float*)d_in[6];
    const float* beta2 = (const float*)d_in[7];
    const float* W3    = (const float*)d_in[8];
    const float* b3    = (const float*)d_in[9];
    float* out = (float*)d_out;

    // ws layout per chunk: cur1 (Tc*B*H*4) | maskbuf (Tc*B*16) | state (512 KB)
    const size_t state_bytes = (size_t)BB * 2 * HH * sizeof(float);
    const size_t per_t = (size_t)BB * (HH * sizeof(float) + 2 * sizeof(unsigned long long));
    size_t avail = ws_size > state_bytes ? ws_size - state_bytes : 0;
    int Tc_max = (int)(avail / per_t);
    if (Tc_max > TT) Tc_max = TT;
    Tc_max = (Tc_max / 256) * 256;
    if (Tc_max < 256) Tc_max = 256;   // ws known >= ~269 MB from round 2

    float* cur1 = (float*)d_ws;
    unsigned long long* maskbuf =
        (unsigned long long*)((char*)d_ws + (size_t)Tc_max * BB * HH * sizeof(float));
    float* state = (float*)((char*)maskbuf + (size_t)Tc_max * BB * 2 * sizeof(unsigned long long));

    int t0 = 0;
    while (t0 < TT) {
        int Tc = (TT - t0 < Tc_max) ? (TT - t0) : Tc_max;
        gemm_cur1<<<dim3(Tc / 256, BB), 256, 0, stream>>>(X, W1, b1, cur1, t0, Tc);
        scan_lif<<<BB * 2, 64, 0, stream>>>(cur1,
                                            (t0 == 0) ? hid : (const float*)state, state,
                                            beta1, W2, b2, beta2, maskbuf, Tc);
        out_k<<<dim3(Tc / 16, BB), 256, 0, stream>>>(maskbuf, W3, b3, out, t0, Tc);
        t0 += Tc;
    }
}